// Round 10
// baseline (261.028 us; speedup 1.0000x reference)
//
#include <hip/hip_runtime.h>
#include <float.h>

#define N_TRAIN 50000
#define NPAD    50176        // 196*256 padded col count
#define NBLK    392          // 128-col blocks (for blkmax/select)
#define NBLK2   196          // 256-col gemm blocks
#define MPAD    1792         // 7*256 padded row count
#define DDIM    384
#define M_ROWS  1568         // 8*196
#define KNN     20
#define K2      24           // candidate-inclusion rank (margin over 20)
#define SELMAX  64           // max refined candidates per row
#define NCLS    21
#define CAPBUF  768
#define CBMAX   256

typedef __attribute__((ext_vector_type(8))) short bf16x8;
typedef __attribute__((ext_vector_type(4))) float f32x4;

#define GLOAD_LDS16(gp, lp) \
  __builtin_amdgcn_global_load_lds((const __attribute__((address_space(1))) void*)(gp), \
                                   (__attribute__((address_space(3))) void*)(lp), 16, 0, 0)
#define WAITVM(N) asm volatile("s_waitcnt vmcnt(" #N ")" ::: "memory")

// round-to-nearest-even f32 -> bf16
static __device__ __forceinline__ unsigned short f2bf(float f) {
  unsigned int u = __float_as_uint(f);
  unsigned int r = (u + 0x7fffu + ((u >> 16) & 1u)) >> 16;
  return (unsigned short)r;
}
// order-preserving f32 -> u32 key
static __device__ __forceinline__ unsigned int flip32(unsigned int u) {
  return (u & 0x80000000u) ? ~u : (u | 0x80000000u);
}

// ---------------- transpose labels [256][50000] i32 -> [50000][256] u8 --------
__global__ __launch_bounds__(256) void transpose_labels(const int* __restrict__ labels,
                                                        unsigned char* __restrict__ labT) {
  __shared__ int tile[64][65];
  const int t  = threadIdx.x;
  const int c0 = blockIdx.x * 64;
  const int r0 = blockIdx.y * 64;
#pragma unroll
  for (int i = 0; i < 16; ++i) {
    int idx = i * 256 + t;
    int r = idx >> 6, c = idx & 63;
    int cc = c0 + c;
    tile[r][c] = (cc < N_TRAIN) ? labels[(size_t)(r0 + r) * N_TRAIN + cc] : 0;
  }
  __syncthreads();
#pragma unroll
  for (int i = 0; i < 16; ++i) {
    int idx = i * 256 + t;
    int c = idx >> 6, r = idx & 63;
    int cc = c0 + c;
    if (cc < N_TRAIN) labT[(size_t)cc * 256 + r0 + r] = (unsigned char)tile[r][c];
  }
}

// ---------------- convert test [1568][384] f32 -> bf16A [1792][384] (pad 0) ---
__global__ __launch_bounds__(256) void conv_bf16A(const float* __restrict__ test,
                                                  unsigned short* __restrict__ bf16A) {
  int idx = blockIdx.x * 256 + threadIdx.x;      // over MPAD*DDIM = 688,128
  if (idx >= MPAD * DDIM) return;
  int row = idx / DDIM;
  bf16A[idx] = (row < M_ROWS) ? f2bf(test[idx]) : (unsigned short)0;
}

// -- fused transpose train [384][50000] f32 -> bhT bf16 [50176][384] + trainT f32
__global__ __launch_bounds__(256) void trans_train_fused(const float* __restrict__ train,
                                                         unsigned short* __restrict__ bhT,
                                                         float* __restrict__ trainT) {
  __shared__ float tile[64][65];
  const int t  = threadIdx.x;
  const int c0 = blockIdx.x * 64;   // col (0..50176)
  const int r0 = blockIdx.y * 64;   // k
#pragma unroll
  for (int i = 0; i < 16; ++i) {
    int idx = i * 256 + t;
    int r = idx >> 6, c = idx & 63;
    int cc = c0 + c;
    tile[r][c] = (cc < N_TRAIN) ? train[(size_t)(r0 + r) * N_TRAIN + cc] : 0.f;
  }
  __syncthreads();
#pragma unroll
  for (int i = 0; i < 16; ++i) {
    int idx = i * 256 + t;
    int c = idx >> 6, r = idx & 63;
    int cc = c0 + c;                 // < 50176 by grid construction
    float v = tile[r][c];
    bhT[(size_t)cc * DDIM + r0 + r] = f2bf(v);
    if (cc < N_TRAIN) trainT[(size_t)cc * DDIM + r0 + r] = v;
  }
}

// ---------------- MFMA bf16 GEMM, 256x256 tile, 8 waves, counted-vmcnt pipeline
// K = 384 -> 6 K-tiles of 64, each computed in 2 K-half phases (12 phases).
// LDS (dynamic, 128 KB u16[65536]): A slot s @ s*16384, B slot s @ 32768+s*16384,
// each [256 rows][64 k] bf16, T2-swizzled: phys k-chunk = logical ^ (row&7).
// Stage S(t+1) half h during phase (t,h) into slot[(t+1)&1] (4 gl_lds/thread).
// vmcnt(4) at h=0 proves S(t) landed; vmcnt never 0 until the last tile.
__global__ __launch_bounds__(512, 2) void mfma_gemm(const unsigned short* __restrict__ bf16A,
                                                    const unsigned short* __restrict__ bhT,
                                                    unsigned short* __restrict__ keybuf,
                                                    unsigned short* __restrict__ blkmax) {
  extern __shared__ unsigned short lds16[];   // 65536 u16 = 128 KB
  const int t = threadIdx.x;

  // bijective XCD chunking: nwg = 1372 = 8*171 + 4
  const int flat = blockIdx.x;
  const int xcd = flat & 7, jj = flat >> 3;
  const int wg = (xcd < 4 ? xcd * 172 : 688 + (xcd - 4) * 171) + jj;
  const int mblk = wg % 7, nblk = wg / 7;       // nblk in [0,196)
  const int m0 = mblk * 256, n0 = nblk * 256;

  const int wid = t >> 6, lane = t & 63;
  const int wr = wid >> 2, wc = wid & 3;        // 2 x 4 waves, wave tile 128x64
  const int l15 = lane & 15, l4 = lane >> 4;
  const int srow = t >> 3;                      // staging row-in-call 0..63
  const int sx   = (t & 7) ^ (srow & 7);        // pre-swizzled source k-chunk

  f32x4 acc[8][4];
  const f32x4 zero = {0.f, 0.f, 0.f, 0.f};
#pragma unroll
  for (int f = 0; f < 8; ++f)
#pragma unroll
    for (int n = 0; n < 4; ++n) acc[f][n] = zero;

  // per-phase stage of tile tk, row-half h (rows h*128..h*128+127 of A and B)
#define STAGE_HALF(tk, h)                                                          \
  {                                                                                \
    const int slot_ = (tk) & 1;                                                    \
    _Pragma("unroll")                                                              \
    for (int j2 = 2 * (h); j2 < 2 * (h) + 2; ++j2) {                               \
      GLOAD_LDS16(bf16A + (size_t)(m0 + j2 * 64 + srow) * DDIM + (tk) * 64 + sx * 8, \
                  &lds16[slot_ * 16384 + j2 * 4096 + wid * 512]);                  \
      GLOAD_LDS16(bhT + (size_t)(n0 + j2 * 64 + srow) * DDIM + (tk) * 64 + sx * 8, \
                  &lds16[32768 + slot_ * 16384 + j2 * 4096 + wid * 512]);          \
    }                                                                              \
  }

  // prologue: stage tile 0 fully
  STAGE_HALF(0, 0);
  STAGE_HALF(0, 1);

#pragma unroll
  for (int p = 0; p < 12; ++p) {
    const int tk = p >> 1, h = p & 1;
    if (tk + 1 < 6) STAGE_HALF(tk + 1, h);
    if (p >= 10)      { WAITVM(0); }
    else if (h == 0)  { WAITVM(4); }
    else              { WAITVM(8); }
    __builtin_amdgcn_s_barrier();
    asm volatile("" ::: "memory");   // no LDS read hoists above the barrier

    const int aBase = (tk & 1) * 16384;
    const int bBase = 32768 + (tk & 1) * 16384;
    const int physc = ((h * 4 + l4) ^ (l15 & 7)) * 8;
    bf16x8 a[8], b[4];
#pragma unroll
    for (int f = 0; f < 8; ++f)
      a[f] = *(const bf16x8*)&lds16[aBase + (wr * 128 + f * 16 + l15) * 64 + physc];
#pragma unroll
    for (int n = 0; n < 4; ++n)
      b[n] = *(const bf16x8*)&lds16[bBase + (wc * 64 + n * 16 + l15) * 64 + physc];

    __builtin_amdgcn_s_setprio(1);
#pragma unroll
    for (int f = 0; f < 8; ++f)
#pragma unroll
      for (int n = 0; n < 4; ++n)
        acc[f][n] = __builtin_amdgcn_mfma_f32_16x16x32_bf16(a[f], b[n], acc[f][n], 0, 0, 0);
    __builtin_amdgcn_s_setprio(0);

    asm volatile("s_waitcnt lgkmcnt(0)" ::: "memory");  // my ds_reads complete
    __builtin_amdgcn_s_barrier();                        // before anyone restages
  }

  // ---- epilogue: swizzled u16 C-tile [256][256] in LDS ----
  __syncthreads();
#pragma unroll
  for (int f = 0; f < 8; ++f) {
    const int row0 = wr * 128 + f * 16 + l4 * 4;
#pragma unroll
    for (int n = 0; n < 4; ++n) {
      const int col = wc * 64 + n * 16 + l15;
      const int cl = col >> 3, ce = col & 7;
#pragma unroll
      for (int r = 0; r < 4; ++r) {
        const int rr = row0 + r;
        unsigned int k16 = flip32(__float_as_uint(acc[f][n][r])) >> 16;
        lds16[rr * 256 + ((cl ^ (rr & 31)) << 3) + ce] = (unsigned short)k16;
      }
    }
  }
  __syncthreads();

  // ---- coalesced readout: 16 x dwordx4 per thread + per-128-col blkmax ----
  const bool boundary = (n0 + 256 > N_TRAIN);
#pragma unroll
  for (int i = 0; i < 16; ++i) {
    int idx = i * 512 + t;                 // 0..8191
    int row = idx >> 5;                    // 0..255
    int cL  = idx & 31;                    // logical 8-u16 chunk
    uint4 v = *(uint4*)&lds16[row * 256 + ((cL ^ (row & 31)) << 3)];
    int c8 = cL * 8;
    if (boundary) {
      int nv = N_TRAIN - (n0 + c8);        // valid halves: j < nv
      v.x &= ((0 < nv) ? 0x0000FFFFu : 0u) | ((1 < nv) ? 0xFFFF0000u : 0u);
      v.y &= ((2 < nv) ? 0x0000FFFFu : 0u) | ((3 < nv) ? 0xFFFF0000u : 0u);
      v.z &= ((4 < nv) ? 0x0000FFFFu : 0u) | ((5 < nv) ? 0xFFFF0000u : 0u);
      v.w &= ((6 < nv) ? 0x0000FFFFu : 0u) | ((7 < nv) ? 0xFFFF0000u : 0u);
    }
    unsigned int mx = v.x & 0xFFFFu;
    mx = max(mx, v.x >> 16); mx = max(mx, v.y & 0xFFFFu); mx = max(mx, v.y >> 16);
    mx = max(mx, v.z & 0xFFFFu); mx = max(mx, v.z >> 16);
    mx = max(mx, v.w & 0xFFFFu); mx = max(mx, v.w >> 16);
    mx = max(mx, (unsigned int)__shfl_xor((int)mx, 1));
    mx = max(mx, (unsigned int)__shfl_xor((int)mx, 2));
    mx = max(mx, (unsigned int)__shfl_xor((int)mx, 4));
    mx = max(mx, (unsigned int)__shfl_xor((int)mx, 8));
    const int grow = m0 + row;
    if (grow < M_ROWS) {
      if ((lane & 15) == 0) {
        int half = (lane >> 4) & 1;        // lanes 0-15/32-47 -> half0, 16-31/48-63 -> half1
        blkmax[(size_t)grow * NBLK + nblk * 2 + half] = (unsigned short)mx;
      }
      *(uint4*)&keybuf[(size_t)grow * NPAD + n0 + c8] = v;
    }
  }
#undef STAGE_HALF
}

// --------- fused tail: exact candidate select -> f64 refine -> softmax -> vote
__global__ __launch_bounds__(256) void tail_fused(const unsigned short* __restrict__ keybuf,
                                                  const unsigned short* __restrict__ blkmax,
                                                  const float* __restrict__ test,
                                                  const float* __restrict__ trainT,
                                                  const unsigned char* __restrict__ labT,
                                                  int* __restrict__ out) {
  const int t = threadIdx.x, m = blockIdx.x;
  __shared__ unsigned short bm[NBLK];
  __shared__ int clist[CBMAX];
  __shared__ int ccnt;
  __shared__ unsigned int smax[256];
  __shared__ unsigned int sbuf[CAPBUF];
  __shared__ short srk[CAPBUF];
  __shared__ unsigned int scnt, sTauA, sTau;
  __shared__ int sC2;
  __shared__ int selC[SELMAX];
  __shared__ double rvs[SELMAX];
  __shared__ double sv2[SELMAX];
  __shared__ int    si2[SELMAX];
  __shared__ double earr[KNN];
  __shared__ double wv[KNN];
  __shared__ int    wi[KNN];

  if (t == 0) { ccnt = 0; scnt = 0u; sC2 = 0; }
  for (int i = t; i < NBLK; i += 256) bm[i] = blkmax[(size_t)m * NBLK + i];
  __syncthreads();

  // candidate 128-col blocks: strict-greater-rank < K2 (superset incl. ties)
  for (int i = t; i < NBLK; i += 256) {
    unsigned short v = bm[i];
    int cgt = 0;
    for (int j = 0; j < NBLK; ++j) cgt += (bm[j] > v) ? 1 : 0;
    if (cgt < K2) { int p = atomicAdd(&ccnt, 1); if (p < CBMAX) clist[p] = i; }
  }
  __syncthreads();
  const int CB = min(ccnt, CBMAX);
  const int TOT = CB * 128;

  // per-thread max over candidate-block keys -> tauB = 24th of 256 maxima
  unsigned int tmx = 0u;
  for (int i = t; i < TOT; i += 256) {
    int col = clist[i >> 7] * 128 + (i & 127);
    unsigned int k = keybuf[(size_t)m * NPAD + col];
    if (k > tmx) tmx = k;
  }
  smax[t] = (tmx << 8) | (unsigned int)(255 - t);
  __syncthreads();
  {
    unsigned int myc = smax[t];
    int rnk = 0;
    for (int j = 0; j < 256; ++j) rnk += (smax[j] > myc) ? 1 : 0;
    if (rnk == K2 - 1) sTauA = myc >> 8;
  }
  __syncthreads();
  const unsigned int tauB = sTauA;

  // collect all candidate keys >= tauB (superset of exact top-24)
  for (int i = t; i < TOT; i += 256) {
    int col = clist[i >> 7] * 128 + (i & 127);
    unsigned int k = keybuf[(size_t)m * NPAD + col];
    if (k >= tauB) {
      unsigned int p = atomicAdd(&scnt, 1u);
      if (p < CAPBUF) sbuf[p] = (k << 16) | (unsigned int)(0xFFFF - col);
    }
  }
  __syncthreads();
  const int C = (int)min(scnt, (unsigned int)CAPBUF);

  for (int s = t; s < C; s += 256) {
    unsigned int e = sbuf[s];
    int rk = 0;
    for (int j = 0; j < C; ++j) rk += (sbuf[j] > e) ? 1 : 0;
    srk[s] = (short)rk;
    if (rk == K2 - 1) sTau = e >> 16;
  }
  __syncthreads();
  const unsigned int tau = sTau;
  for (int s = t; s < C; s += 256) {
    unsigned int e = sbuf[s];
    int rk = (int)srk[s];
    if ((e >> 16) >= tau && rk < SELMAX) {
      selC[rk] = 0xFFFF - (int)(e & 0xFFFFu);
      atomicMax(&sC2, rk + 1);
    }
  }
  __syncthreads();
  const int C2 = sC2 < SELMAX ? sC2 : SELMAX;   // 24 <= C2 <= 64

  // ---- f64 refine of C2 cands (4 waves split cands, lanes over d) ----
  const int wid = t >> 6, lane = t & 63;
  float tr[DDIM / 64];
#pragma unroll
  for (int dd = 0; dd < DDIM / 64; ++dd)
    tr[dd] = test[(size_t)m * DDIM + dd * 64 + lane];
#pragma unroll 1
  for (int c = wid; c < C2; c += 4) {
    const float* Tc = trainT + (size_t)selC[c] * DDIM;
    double s = 0.0;
#pragma unroll
    for (int dd = 0; dd < DDIM / 64; ++dd)
      s += (double)tr[dd] * (double)Tc[dd * 64 + lane];
#pragma unroll
    for (int off = 32; off > 0; off >>= 1) s += __shfl_xor(s, off);
    if (lane == 0) rvs[c] = s;
  }
  __syncthreads();

  if (t < C2) {
    double v = rvs[t]; int id = selC[t];
    int r = 0;
    for (int n = 0; n < C2; ++n)
      r += (rvs[n] > v || (rvs[n] == v && selC[n] < id)) ? 1 : 0;
    sv2[r] = v; si2[r] = id;
  }
  __syncthreads();

  if (t < KNN) earr[t] = exp(sv2[t] - sv2[0]);
  __syncthreads();
  if (t < KNN) {
    double ssum = 0.0;
    for (int k = 0; k < KNN; ++k) ssum += earr[k];
    wv[t] = earr[t] / ssum;
    wi[t] = si2[t];
  }
  __syncthreads();

  // ---- per-pixel weighted vote (f64) + argmax ----
  unsigned int packed[5];
#pragma unroll
  for (int q = 0; q < 5; ++q) {
    unsigned int p = 0;
#pragma unroll
    for (int j = 0; j < 4; ++j)
      p |= (unsigned int)labT[(size_t)wi[q * 4 + j] * 256 + t] << (8 * j);
    packed[q] = p;
  }
  double best = -1.0; int bc = 0;
#pragma unroll 1
  for (int c = 0; c < NCLS; ++c) {
    double s = 0.0;
#pragma unroll
    for (int k = 0; k < KNN; ++k) {
      unsigned int lab = (packed[k >> 2] >> ((k & 3) * 8)) & 255u;
      s += (lab == (unsigned int)c) ? wv[k] : 0.0;
    }
    if (s > best) { best = s; bc = c; }
  }
  const int b = m / 196, p = m % 196;
  const int py = p / 14, px = p % 14;
  const int i = t >> 4, j = t & 15;
  out[((size_t)b * 224 + py * 16 + i) * 224 + px * 16 + j] = bc;
}

// ---------------- launch ------------------------------------------------------
// ws layout (bytes), total 288,092,672 (< ~307 MB poisoned ws; NO aliasing):
//   labT    @ 0           : 12,800,000
//   bf16A   @ 12,800,000  :  1,376,256  (u16 [1792][384])
//   bhT     @ 14,176,256  : 38,535,168  (u16 [50176][384])
//   keybuf  @ 52,711,424  : 157,351,936 (u16 [1568][50176])
//   trainT  @ 210,063,360 : 76,800,000  (f32 [50000][384])
//   blkmax  @ 286,863,360 :  1,229,312  (u16 [1568][392])
extern "C" void kernel_launch(void* const* d_in, const int* in_sizes, int n_in,
                              void* d_out, int out_size, void* d_ws, size_t ws_size,
                              hipStream_t stream) {
  const float* test  = (const float*)d_in[0];   // [1568][384]
  const float* train = (const float*)d_in[1];   // [384][50000]
  const int* labels  = (const int*)d_in[2];     // [256][50000]
  int* out = (int*)d_out;
  char* ws = (char*)d_ws;

  unsigned char*  labT    = (unsigned char*)ws;
  unsigned short* bf16A   = (unsigned short*)(ws + 12800000);
  unsigned short* bhT     = (unsigned short*)(ws + 14176256);
  unsigned short* keybuf  = (unsigned short*)(ws + 52711424);
  float*          trainT  = (float*)(ws + 210063360);
  unsigned short* blkmax  = (unsigned short*)(ws + 286863360);

  transpose_labels<<<dim3(782, 4), 256, 0, stream>>>(labels, labT);
  conv_bf16A<<<dim3((MPAD * DDIM + 255) / 256), 256, 0, stream>>>(test, bf16A);
  trans_train_fused<<<dim3(784, 6), 256, 0, stream>>>(train, bhT, trainT);
  mfma_gemm<<<dim3(7 * NBLK2), 512, 131072, stream>>>(bf16A, bhT, keybuf, blkmax);
  tail_fused<<<dim3(M_ROWS), 256, 0, stream>>>(keybuf, blkmax, test, trainT, labT, out);
}

// Round 11
// 257.943 us; speedup vs baseline: 1.0120x; 1.0120x over previous
//
#include <hip/hip_runtime.h>
#include <float.h>

#define N_TRAIN 50000
#define NPAD    50176        // 3136*16 padded col count
#define NBLK    392          // 128-col blocks (for blkmax/select)
#define MPAD    1792         // 14*128 padded row count
#define DDIM    384
#define M_ROWS  1568         // 8*196
#define KNN     20
#define K2      24           // candidate-inclusion rank (margin over 20)
#define SELMAX  64           // max refined candidates per row
#define NCLS    21
#define CAPBUF  768
#define CBMAX   256

typedef __attribute__((ext_vector_type(8))) short bf16x8;
typedef __attribute__((ext_vector_type(4))) float f32x4;

// round-to-nearest-even f32 -> bf16
static __device__ __forceinline__ unsigned short f2bf(float f) {
  unsigned int u = __float_as_uint(f);
  unsigned int r = (u + 0x7fffu + ((u >> 16) & 1u)) >> 16;
  return (unsigned short)r;
}
// order-preserving f32 -> u32 key
static __device__ __forceinline__ unsigned int flip32(unsigned int u) {
  return (u & 0x80000000u) ? ~u : (u | 0x80000000u);
}

// ---------------- transpose labels [256][50000] i32 -> [50000][256] u8 --------
__global__ __launch_bounds__(256) void transpose_labels(const int* __restrict__ labels,
                                                        unsigned char* __restrict__ labT) {
  __shared__ int tile[64][65];
  const int t  = threadIdx.x;
  const int c0 = blockIdx.x * 64;
  const int r0 = blockIdx.y * 64;
#pragma unroll
  for (int i = 0; i < 16; ++i) {
    int idx = i * 256 + t;
    int r = idx >> 6, c = idx & 63;
    int cc = c0 + c;
    tile[r][c] = (cc < N_TRAIN) ? labels[(size_t)(r0 + r) * N_TRAIN + cc] : 0;
  }
  __syncthreads();
#pragma unroll
  for (int i = 0; i < 16; ++i) {
    int idx = i * 256 + t;
    int c = idx >> 6, r = idx & 63;
    int cc = c0 + c;
    if (cc < N_TRAIN) labT[(size_t)cc * 256 + r0 + r] = (unsigned char)tile[r][c];
  }
}

// ------- pack test -> Apack fragment-major: [mt=112][kc=12][lane=64][8] bf16 ---
// element: A[row = mt*16 + (lane&15)][k = kc*32 + (lane>>4)*8 + j]
__global__ __launch_bounds__(256) void conv_Apack(const float* __restrict__ test,
                                                  unsigned short* __restrict__ Apack) {
  int o = blockIdx.x * 256 + threadIdx.x;        // over 112*12*512 = 688,128
  if (o >= (MPAD / 16) * 12 * 512) return;
  int j = o & 7;
  int l = (o >> 3) & 63;
  int kcmt = o >> 9;
  int kc = kcmt % 12, mt = kcmt / 12;
  int row = mt * 16 + (l & 15);
  int k = kc * 32 + (l >> 4) * 8 + j;
  Apack[o] = (row < M_ROWS) ? f2bf(test[(size_t)row * DDIM + k]) : (unsigned short)0;
}

// -- fused: train [384][50000] f32 -> Bpack frag-major bf16 + trainT f32 -------
// Bpack: [nt=3136][kc=12][lane=64][8]; element B[col=nt*16+(l&15)][k=kc*32+(l>>4)*8+j]
__global__ __launch_bounds__(256) void trans_train_fused(const float* __restrict__ train,
                                                         unsigned short* __restrict__ Bpack,
                                                         float* __restrict__ trainT) {
  __shared__ float tile[64][65];   // [k-in-tile][col-in-tile]
  const int t  = threadIdx.x;
  const int c0 = blockIdx.x * 64;   // col base (0..50176)
  const int r0 = blockIdx.y * 64;   // k base (0..384)
#pragma unroll
  for (int i = 0; i < 16; ++i) {
    int idx = i * 256 + t;
    int r = idx >> 6, c = idx & 63;
    int cc = c0 + c;
    tile[r][c] = (cc < N_TRAIN) ? train[(size_t)(r0 + r) * N_TRAIN + cc] : 0.f;
  }
  __syncthreads();
  // Bpack writes: 512 units of (col, koctLocal); each = 16 B contiguous
#pragma unroll
  for (int it = 0; it < 2; ++it) {
    int u = it * 256 + t;
    int c = u & 63, koctL = u >> 6;            // koctL 0..7
    int col = c0 + c;
    int koct = (r0 >> 3) + koctL;
    int kc = koct >> 2, l4 = koct & 3;
    int nt = col >> 4, l15 = col & 15;
    size_t base = ((size_t)(nt * 12 + kc) * 64 + l4 * 16 + l15) * 8;
    ushort4 h0, h1;
    h0.x = f2bf(tile[koctL * 8 + 0][c]); h0.y = f2bf(tile[koctL * 8 + 1][c]);
    h0.z = f2bf(tile[koctL * 8 + 2][c]); h0.w = f2bf(tile[koctL * 8 + 3][c]);
    h1.x = f2bf(tile[koctL * 8 + 4][c]); h1.y = f2bf(tile[koctL * 8 + 5][c]);
    h1.z = f2bf(tile[koctL * 8 + 6][c]); h1.w = f2bf(tile[koctL * 8 + 7][c]);
    *(ushort4*)&Bpack[base]     = h0;
    *(ushort4*)&Bpack[base + 4] = h1;
  }
  // trainT writes (f32 transpose)
#pragma unroll
  for (int i = 0; i < 16; ++i) {
    int idx = i * 256 + t;
    int c = idx >> 6, r = idx & 63;
    int cc = c0 + c;
    if (cc < N_TRAIN) trainT[(size_t)cc * DDIM + r0 + r] = tile[r][c];
  }
}

// ---------------- MFMA bf16 GEMM — no-LDS fragment streaming ------------------
// 128x256 block tile, 4 waves (wave = 128x64), K-loop = 12 x {12 coalesced
// 1KB frag loads from L2 + 32 MFMA}. No barriers/staging in the loop.
// Epilogue: swizzled u16 C-tile in 64KB LDS -> coalesced dwordx4 key stores
// + per-128-col row max (blkmax).
__global__ __launch_bounds__(256, 2) void mfma_gemm(const unsigned short* __restrict__ Apack,
                                                    const unsigned short* __restrict__ Bpack,
                                                    unsigned short* __restrict__ keybuf,
                                                    unsigned short* __restrict__ blkmax) {
  __shared__ unsigned short ct[128 * 256];   // 64 KB, epilogue only
  const int t = threadIdx.x;

  // bijective XCD chunking: nwg = 2744 = 8*343 exactly
  const int flat = blockIdx.x;
  const int wg = (flat & 7) * 343 + (flat >> 3);
  const int mblk = wg % 14, nblk = wg / 14;   // 14 consecutive wg share nblk (B L2-local)
  const int m0 = mblk * 128, n0 = nblk * 256;

  const int wc = t >> 6, lane = t & 63;       // 4 waves: cols wc*64..wc*64+63
  const int l15 = lane & 15, l4 = lane >> 4;

  const unsigned short* Ab = Apack + (size_t)(mblk * 8) * 12 * 512;
  const unsigned short* Bb = Bpack + (size_t)(nblk * 16 + wc * 4) * 12 * 512;

  f32x4 acc[8][4];
  const f32x4 zero = {0.f, 0.f, 0.f, 0.f};
#pragma unroll
  for (int f = 0; f < 8; ++f)
#pragma unroll
    for (int n = 0; n < 4; ++n) acc[f][n] = zero;

  for (int kc = 0; kc < 12; ++kc) {
    bf16x8 a[8], b[4];
#pragma unroll
    for (int f = 0; f < 8; ++f)
      a[f] = *(const bf16x8*)&Ab[((size_t)(f * 12 + kc) * 64 + lane) * 8];
#pragma unroll
    for (int n = 0; n < 4; ++n)
      b[n] = *(const bf16x8*)&Bb[((size_t)(n * 12 + kc) * 64 + lane) * 8];
#pragma unroll
    for (int f = 0; f < 8; ++f)
#pragma unroll
      for (int n = 0; n < 4; ++n)
        acc[f][n] = __builtin_amdgcn_mfma_f32_16x16x32_bf16(a[f], b[n], acc[f][n], 0, 0, 0);
  }

  // ---- epilogue: swizzled u16 C-tile [128][256] in LDS ----
#pragma unroll
  for (int f = 0; f < 8; ++f) {
    const int row0 = f * 16 + l4 * 4;
#pragma unroll
    for (int n = 0; n < 4; ++n) {
      const int col = wc * 64 + n * 16 + l15;
      const int cl = col >> 3, ce = col & 7;
#pragma unroll
      for (int r = 0; r < 4; ++r) {
        const int rr = row0 + r;
        unsigned int k16 = flip32(__float_as_uint(acc[f][n][r])) >> 16;
        ct[rr * 256 + ((cl ^ (rr & 31)) << 3) + ce] = (unsigned short)k16;
      }
    }
  }
  __syncthreads();

  // ---- coalesced readout: 16 x dwordx4 per thread + per-128-col blkmax ----
  const bool boundary = (n0 + 256 > N_TRAIN);
#pragma unroll
  for (int i = 0; i < 16; ++i) {
    int idx = i * 256 + t;                 // 0..4095
    int row = idx >> 5;                    // 0..127
    int cL  = idx & 31;                    // logical 8-u16 chunk
    uint4 v = *(uint4*)&ct[row * 256 + ((cL ^ (row & 31)) << 3)];
    int c8 = cL * 8;
    if (boundary) {
      int nv = N_TRAIN - (n0 + c8);        // valid halves: j < nv
      v.x &= ((0 < nv) ? 0x0000FFFFu : 0u) | ((1 < nv) ? 0xFFFF0000u : 0u);
      v.y &= ((2 < nv) ? 0x0000FFFFu : 0u) | ((3 < nv) ? 0xFFFF0000u : 0u);
      v.z &= ((4 < nv) ? 0x0000FFFFu : 0u) | ((5 < nv) ? 0xFFFF0000u : 0u);
      v.w &= ((6 < nv) ? 0x0000FFFFu : 0u) | ((7 < nv) ? 0xFFFF0000u : 0u);
    }
    unsigned int mx = v.x & 0xFFFFu;
    mx = max(mx, v.x >> 16); mx = max(mx, v.y & 0xFFFFu); mx = max(mx, v.y >> 16);
    mx = max(mx, v.z & 0xFFFFu); mx = max(mx, v.z >> 16);
    mx = max(mx, v.w & 0xFFFFu); mx = max(mx, v.w >> 16);
    mx = max(mx, (unsigned int)__shfl_xor((int)mx, 1));
    mx = max(mx, (unsigned int)__shfl_xor((int)mx, 2));
    mx = max(mx, (unsigned int)__shfl_xor((int)mx, 4));
    mx = max(mx, (unsigned int)__shfl_xor((int)mx, 8));
    const int grow = m0 + row;
    if (grow < M_ROWS) {
      if ((lane & 15) == 0) {
        int half = (lane >> 4) & 1;        // cL 0-15 -> cols 0-127, 16-31 -> 128-255
        blkmax[(size_t)grow * NBLK + nblk * 2 + half] = (unsigned short)mx;
      }
      *(uint4*)&keybuf[(size_t)grow * NPAD + n0 + c8] = v;
    }
  }
}

// --------- fused tail: exact candidate select -> f64 refine -> softmax -> vote
__global__ __launch_bounds__(256) void tail_fused(const unsigned short* __restrict__ keybuf,
                                                  const unsigned short* __restrict__ blkmax,
                                                  const float* __restrict__ test,
                                                  const float* __restrict__ trainT,
                                                  const unsigned char* __restrict__ labT,
                                                  int* __restrict__ out) {
  const int t = threadIdx.x, m = blockIdx.x;
  __shared__ unsigned short bm[NBLK];
  __shared__ int clist[CBMAX];
  __shared__ int ccnt;
  __shared__ unsigned int smax[256];
  __shared__ unsigned int sbuf[CAPBUF];
  __shared__ short srk[CAPBUF];
  __shared__ unsigned int scnt, sTauA, sTau;
  __shared__ int sC2;
  __shared__ int selC[SELMAX];
  __shared__ double rvs[SELMAX];
  __shared__ double sv2[SELMAX];
  __shared__ int    si2[SELMAX];
  __shared__ double earr[KNN];
  __shared__ double wv[KNN];
  __shared__ int    wi[KNN];

  if (t == 0) { ccnt = 0; scnt = 0u; sC2 = 0; }
  for (int i = t; i < NBLK; i += 256) bm[i] = blkmax[(size_t)m * NBLK + i];
  __syncthreads();

  // candidate 128-col blocks: strict-greater-rank < K2 (superset incl. ties)
  for (int i = t; i < NBLK; i += 256) {
    unsigned short v = bm[i];
    int cgt = 0;
    for (int j = 0; j < NBLK; ++j) cgt += (bm[j] > v) ? 1 : 0;
    if (cgt < K2) { int p = atomicAdd(&ccnt, 1); if (p < CBMAX) clist[p] = i; }
  }
  __syncthreads();
  const int CB = min(ccnt, CBMAX);
  const int TOT = CB * 128;

  // per-thread max over candidate-block keys -> tauB = 24th of 256 maxima
  unsigned int tmx = 0u;
  for (int i = t; i < TOT; i += 256) {
    int col = clist[i >> 7] * 128 + (i & 127);
    unsigned int k = keybuf[(size_t)m * NPAD + col];
    if (k > tmx) tmx = k;
  }
  smax[t] = (tmx << 8) | (unsigned int)(255 - t);
  __syncthreads();
  {
    unsigned int myc = smax[t];
    int rnk = 0;
    for (int j = 0; j < 256; ++j) rnk += (smax[j] > myc) ? 1 : 0;
    if (rnk == K2 - 1) sTauA = myc >> 8;
  }
  __syncthreads();
  const unsigned int tauB = sTauA;

  // collect all candidate keys >= tauB (superset of exact top-24)
  for (int i = t; i < TOT; i += 256) {
    int col = clist[i >> 7] * 128 + (i & 127);
    unsigned int k = keybuf[(size_t)m * NPAD + col];
    if (k >= tauB) {
      unsigned int p = atomicAdd(&scnt, 1u);
      if (p < CAPBUF) sbuf[p] = (k << 16) | (unsigned int)(0xFFFF - col);
    }
  }
  __syncthreads();
  const int C = (int)min(scnt, (unsigned int)CAPBUF);

  for (int s = t; s < C; s += 256) {
    unsigned int e = sbuf[s];
    int rk = 0;
    for (int j = 0; j < C; ++j) rk += (sbuf[j] > e) ? 1 : 0;
    srk[s] = (short)rk;
    if (rk == K2 - 1) sTau = e >> 16;
  }
  __syncthreads();
  const unsigned int tau = sTau;
  for (int s = t; s < C; s += 256) {
    unsigned int e = sbuf[s];
    int rk = (int)srk[s];
    if ((e >> 16) >= tau && rk < SELMAX) {
      selC[rk] = 0xFFFF - (int)(e & 0xFFFFu);
      atomicMax(&sC2, rk + 1);
    }
  }
  __syncthreads();
  const int C2 = sC2 < SELMAX ? sC2 : SELMAX;   // 24 <= C2 <= 64

  // ---- f64 refine of C2 cands (4 waves split cands, lanes over d) ----
  const int wid = t >> 6, lane = t & 63;
  float tr[DDIM / 64];
#pragma unroll
  for (int dd = 0; dd < DDIM / 64; ++dd)
    tr[dd] = test[(size_t)m * DDIM + dd * 64 + lane];
#pragma unroll 1
  for (int c = wid; c < C2; c += 4) {
    const float* Tc = trainT + (size_t)selC[c] * DDIM;
    double s = 0.0;
#pragma unroll
    for (int dd = 0; dd < DDIM / 64; ++dd)
      s += (double)tr[dd] * (double)Tc[dd * 64 + lane];
#pragma unroll
    for (int off = 32; off > 0; off >>= 1) s += __shfl_xor(s, off);
    if (lane == 0) rvs[c] = s;
  }
  __syncthreads();

  if (t < C2) {
    double v = rvs[t]; int id = selC[t];
    int r = 0;
    for (int n = 0; n < C2; ++n)
      r += (rvs[n] > v || (rvs[n] == v && selC[n] < id)) ? 1 : 0;
    sv2[r] = v; si2[r] = id;
  }
  __syncthreads();

  if (t < KNN) earr[t] = exp(sv2[t] - sv2[0]);
  __syncthreads();
  if (t < KNN) {
    double ssum = 0.0;
    for (int k = 0; k < KNN; ++k) ssum += earr[k];
    wv[t] = earr[t] / ssum;
    wi[t] = si2[t];
  }
  __syncthreads();

  // ---- per-pixel weighted vote (f64) + argmax ----
  unsigned int packed[5];
#pragma unroll
  for (int q = 0; q < 5; ++q) {
    unsigned int p = 0;
#pragma unroll
    for (int j = 0; j < 4; ++j)
      p |= (unsigned int)labT[(size_t)wi[q * 4 + j] * 256 + t] << (8 * j);
    packed[q] = p;
  }
  double best = -1.0; int bc = 0;
#pragma unroll 1
  for (int c = 0; c < NCLS; ++c) {
    double s = 0.0;
#pragma unroll
    for (int k = 0; k < KNN; ++k) {
      unsigned int lab = (packed[k >> 2] >> ((k & 3) * 8)) & 255u;
      s += (lab == (unsigned int)c) ? wv[k] : 0.0;
    }
    if (s > best) { best = s; bc = c; }
  }
  const int b = m / 196, p = m % 196;
  const int py = p / 14, px = p % 14;
  const int i = t >> 4, j = t & 15;
  out[((size_t)b * 224 + py * 16 + i) * 224 + px * 16 + j] = bc;
}

// ---------------- launch ------------------------------------------------------
// ws layout (bytes), total 288,092,672 (< ~307 MB poisoned ws; NO aliasing):
//   labT    @ 0           : 12,800,000
//   Apack   @ 12,800,000  :  1,376,256  (u16 [112][12][64][8])
//   Bpack   @ 14,176,256  : 38,535,168  (u16 [3136][12][64][8])
//   keybuf  @ 52,711,424  : 157,351,936 (u16 [1568][50176])
//   trainT  @ 210,063,360 : 76,800,000  (f32 [50000][384])
//   blkmax  @ 286,863,360 :  1,229,312  (u16 [1568][392])
extern "C" void kernel_launch(void* const* d_in, const int* in_sizes, int n_in,
                              void* d_out, int out_size, void* d_ws, size_t ws_size,
                              hipStream_t stream) {
  const float* test  = (const float*)d_in[0];   // [1568][384]
  const float* train = (const float*)d_in[1];   // [384][50000]
  const int* labels  = (const int*)d_in[2];     // [256][50000]
  int* out = (int*)d_out;
  char* ws = (char*)d_ws;

  unsigned char*  labT    = (unsigned char*)ws;
  unsigned short* Apack   = (unsigned short*)(ws + 12800000);
  unsigned short* Bpack   = (unsigned short*)(ws + 14176256);
  unsigned short* keybuf  = (unsigned short*)(ws + 52711424);
  float*          trainT  = (float*)(ws + 210063360);
  unsigned short* blkmax  = (unsigned short*)(ws + 286863360);

  transpose_labels<<<dim3(782, 4), 256, 0, stream>>>(labels, labT);
  conv_Apack<<<dim3(2688), 256, 0, stream>>>(test, Apack);
  trans_train_fused<<<dim3(784, 6), 256, 0, stream>>>(train, Bpack, trainT);
  mfma_gemm<<<dim3(2744), 256, 0, stream>>>(Apack, Bpack, keybuf, blkmax);
  tail_fused<<<dim3(M_ROWS), 256, 0, stream>>>(keybuf, blkmax, test, trainT, labT, out);
}

// Round 12
// 238.110 us; speedup vs baseline: 1.0963x; 1.0833x over previous
//
#include <hip/hip_runtime.h>
#include <float.h>

#define N_TRAIN 50000
#define NPAD    50176        // 196*256 padded col count
#define NBLKG   196          // 256-col gemm blocks
#define MPAD    1600         // 25*64 padded row count
#define DDIM    384
#define M_ROWS  1568         // 8*196
#define KNN     20
#define K2      24           // candidate-inclusion rank (margin over 20)
#define SELMAX  64           // max refined candidates per row
#define NCLS    21
#define CAPBUF  768
#define NENT    784          // 196*4 shortlist entries per row

typedef __attribute__((ext_vector_type(8))) short bf16x8;
typedef __attribute__((ext_vector_type(4))) float f32x4;

// round-to-nearest-even f32 -> bf16
static __device__ __forceinline__ unsigned short f2bf(float f) {
  unsigned int u = __float_as_uint(f);
  unsigned int r = (u + 0x7fffu + ((u >> 16) & 1u)) >> 16;
  return (unsigned short)r;
}
static __device__ __forceinline__ float bf2f(unsigned short h) {
  return __uint_as_float(((unsigned int)h) << 16);
}
// order-preserving f32 -> u32 key
static __device__ __forceinline__ unsigned int flip32(unsigned int u) {
  return (u & 0x80000000u) ? ~u : (u | 0x80000000u);
}

#define CSW(x, y) { unsigned int _hi = max(x, y); unsigned int _lo = min(x, y); x = _hi; y = _lo; }

// ---------------- transpose labels [256][50000] i32 -> [50000][256] u8 --------
__global__ __launch_bounds__(256) void transpose_labels(const int* __restrict__ labels,
                                                        unsigned char* __restrict__ labT) {
  __shared__ int tile[64][65];
  const int t  = threadIdx.x;
  const int c0 = blockIdx.x * 64;
  const int r0 = blockIdx.y * 64;
#pragma unroll
  for (int i = 0; i < 16; ++i) {
    int idx = i * 256 + t;
    int r = idx >> 6, c = idx & 63;
    int cc = c0 + c;
    tile[r][c] = (cc < N_TRAIN) ? labels[(size_t)(r0 + r) * N_TRAIN + cc] : 0;
  }
  __syncthreads();
#pragma unroll
  for (int i = 0; i < 16; ++i) {
    int idx = i * 256 + t;
    int c = idx >> 6, r = idx & 63;
    int cc = c0 + c;
    if (cc < N_TRAIN) labT[(size_t)cc * 256 + r0 + r] = (unsigned char)tile[r][c];
  }
}

// ------- pack test -> Apack fragment-major: [mt=100][kc=12][lane=64][8] bf16 ---
// element: A[row = mt*16 + (lane&15)][k = kc*32 + (lane>>4)*8 + j]
__global__ __launch_bounds__(256) void conv_Apack(const float* __restrict__ test,
                                                  unsigned short* __restrict__ Apack) {
  int o = blockIdx.x * 256 + threadIdx.x;        // over 100*12*512 = 614,400
  if (o >= (MPAD / 16) * 12 * 512) return;
  int j = o & 7;
  int l = (o >> 3) & 63;
  int kcmt = o >> 9;
  int kc = kcmt % 12, mt = kcmt / 12;
  int row = mt * 16 + (l & 15);
  int k = kc * 32 + (l >> 4) * 8 + j;
  Apack[o] = (row < M_ROWS) ? f2bf(test[(size_t)row * DDIM + k]) : (unsigned short)0;
}

// -- fused: train [384][50000] f32 -> Bpack frag-major bf16 + trainT f32 -------
// Bpack: [nt=3136][kc=12][lane=64][8]; element B[col=nt*16+(l&15)][k=kc*32+(l>>4)*8+j]
__global__ __launch_bounds__(256) void trans_train_fused(const float* __restrict__ train,
                                                         unsigned short* __restrict__ Bpack,
                                                         float* __restrict__ trainT) {
  __shared__ float tile[64][65];   // [k-in-tile][col-in-tile]
  const int t  = threadIdx.x;
  const int c0 = blockIdx.x * 64;   // col base (0..50176)
  const int r0 = blockIdx.y * 64;   // k base (0..384)
#pragma unroll
  for (int i = 0; i < 16; ++i) {
    int idx = i * 256 + t;
    int r = idx >> 6, c = idx & 63;
    int cc = c0 + c;
    tile[r][c] = (cc < N_TRAIN) ? train[(size_t)(r0 + r) * N_TRAIN + cc] : 0.f;
  }
  __syncthreads();
#pragma unroll
  for (int it = 0; it < 2; ++it) {
    int u = it * 256 + t;
    int c = u & 63, koctL = u >> 6;            // koctL 0..7
    int col = c0 + c;
    int koct = (r0 >> 3) + koctL;
    int kc = koct >> 2, l4 = koct & 3;
    int nt = col >> 4, l15 = col & 15;
    size_t base = ((size_t)(nt * 12 + kc) * 64 + l4 * 16 + l15) * 8;
    ushort4 h0, h1;
    h0.x = f2bf(tile[koctL * 8 + 0][c]); h0.y = f2bf(tile[koctL * 8 + 1][c]);
    h0.z = f2bf(tile[koctL * 8 + 2][c]); h0.w = f2bf(tile[koctL * 8 + 3][c]);
    h1.x = f2bf(tile[koctL * 8 + 4][c]); h1.y = f2bf(tile[koctL * 8 + 5][c]);
    h1.z = f2bf(tile[koctL * 8 + 6][c]); h1.w = f2bf(tile[koctL * 8 + 7][c]);
    *(ushort4*)&Bpack[base]     = h0;
    *(ushort4*)&Bpack[base + 4] = h1;
  }
#pragma unroll
  for (int i = 0; i < 16; ++i) {
    int idx = i * 256 + t;
    int c = idx >> 6, r = idx & 63;
    int cc = c0 + c;
    if (cc < N_TRAIN) trainT[(size_t)cc * DDIM + r0 + r] = tile[r][c];
  }
}

// ---------------- MFMA bf16 GEMM -> per-(row, 256-col block) top-4 shortlist --
// 64x256 block tile, 4 waves (wave = 64rows x 64cols), register streaming.
// Epilogue: per-row top-4 via in-lane sort4 + bitonic lane merges; cross-wave
// merge in 4KB LDS; writes 16 B per (row, nblk). No key matrix materialized.
__global__ __launch_bounds__(256, 3) void mfma_gemm(const unsigned short* __restrict__ Apack,
                                                    const unsigned short* __restrict__ Bpack,
                                                    unsigned int* __restrict__ toplist) {
  __shared__ unsigned int ldsT[64 * 16];   // [row][wave*4 + slot]
  const int t = threadIdx.x;

  // bijective XCD chunking: nwg = 4900 = 4*613 + 4*612
  const int flat = blockIdx.x;
  const int xcd = flat & 7, jj = flat >> 3;
  const int wg = (xcd < 4 ? xcd * 613 : 2452 + (xcd - 4) * 612) + jj;
  const int mblk = wg % 25, nblk = wg / 25;   // 25 consecutive wg share nblk (B L2-local)
  const int m0 = mblk * 64, n0 = nblk * 256;

  const int wc = t >> 6, lane = t & 63;       // 4 waves: cols wc*64..wc*64+63
  const int l15 = lane & 15, l4 = lane >> 4;

  const unsigned short* Ab = Apack + (size_t)(mblk * 4) * 12 * 512;
  const unsigned short* Bb = Bpack + (size_t)(nblk * 16 + wc * 4) * 12 * 512;

  f32x4 acc[4][4];
  const f32x4 zero = {0.f, 0.f, 0.f, 0.f};
#pragma unroll
  for (int f = 0; f < 4; ++f)
#pragma unroll
    for (int n = 0; n < 4; ++n) acc[f][n] = zero;

  for (int kc = 0; kc < 12; ++kc) {
    bf16x8 a[4], b[4];
#pragma unroll
    for (int f = 0; f < 4; ++f)
      a[f] = *(const bf16x8*)&Ab[((size_t)(f * 12 + kc) * 64 + lane) * 8];
#pragma unroll
    for (int n = 0; n < 4; ++n)
      b[n] = *(const bf16x8*)&Bb[((size_t)(n * 12 + kc) * 64 + lane) * 8];
#pragma unroll
    for (int f = 0; f < 4; ++f)
#pragma unroll
      for (int n = 0; n < 4; ++n)
        acc[f][n] = __builtin_amdgcn_mfma_f32_16x16x32_bf16(a[f], b[n], acc[f][n], 0, 0, 0);
  }

  // ---- epilogue: per-row top-4 over this wave's 64 cols, then cross-wave ----
#pragma unroll
  for (int f = 0; f < 4; ++f) {
#pragma unroll
    for (int r = 0; r < 4; ++r) {
      const int row = f * 16 + l4 * 4 + r;
      unsigned int e[4];
#pragma unroll
      for (int n = 0; n < 4; ++n) {
        int col = n0 + wc * 64 + n * 16 + l15;
        unsigned int k16 = flip32(__float_as_uint(acc[f][n][r])) >> 16;
        e[n] = (col < N_TRAIN) ? ((k16 << 16) | (0xFFFFu - (unsigned int)col)) : 0u;
      }
      // sort4 desc
      CSW(e[0], e[1]); CSW(e[2], e[3]); CSW(e[0], e[2]); CSW(e[1], e[3]); CSW(e[1], e[2]);
      // butterfly merge across the 16 l15-lanes (strides 1,2,4,8)
#pragma unroll
      for (int st = 1; st <= 8; st <<= 1) {
        unsigned int p0 = (unsigned int)__shfl_xor((int)e[0], st);
        unsigned int p1 = (unsigned int)__shfl_xor((int)e[1], st);
        unsigned int p2 = (unsigned int)__shfl_xor((int)e[2], st);
        unsigned int p3 = (unsigned int)__shfl_xor((int)e[3], st);
        unsigned int t0 = max(e[0], p3), t1 = max(e[1], p2);
        unsigned int t2 = max(e[2], p1), t3 = max(e[3], p0);
        CSW(t0, t2); CSW(t1, t3); CSW(t0, t1); CSW(t2, t3);
        e[0] = t0; e[1] = t1; e[2] = t2; e[3] = t3;
      }
      if (l15 == 0) {
        uint4 v; v.x = e[0]; v.y = e[1]; v.z = e[2]; v.w = e[3];
        *(uint4*)&ldsT[row * 16 + wc * 4] = v;
      }
    }
  }
  __syncthreads();

  // ---- final: per row merge the 4 wave-lists (t < 64) ----
  if (t < 64) {
    const int grow = m0 + t;
    if (grow < M_ROWS) {
      unsigned int v[16];
#pragma unroll
      for (int q = 0; q < 4; ++q)
        *(uint4*)&v[q * 4] = *(uint4*)&ldsT[t * 16 + q * 4];
      unsigned int o0 = 0, o1 = 0, o2 = 0, o3 = 0;
#pragma unroll
      for (int j = 0; j < 16; ++j) {
        int rk = 0;
#pragma unroll
        for (int k = 0; k < 16; ++k) rk += (v[k] > v[j]) ? 1 : 0;
        if (rk == 0) o0 = v[j];
        else if (rk == 1) o1 = v[j];
        else if (rk == 2) o2 = v[j];
        else if (rk == 3) o3 = v[j];
      }
      uint4 w; w.x = o0; w.y = o1; w.z = o2; w.w = o3;
      *(uint4*)&toplist[(size_t)grow * NENT + nblk * 4] = w;
    }
  }
}

// --------- fused tail: shortlist select (+rare rescan) -> f64 refine -> vote --
__global__ __launch_bounds__(256) void tail_fused(const unsigned int* __restrict__ toplist,
                                                  const float* __restrict__ test,
                                                  const float* __restrict__ trainT,
                                                  const unsigned char* __restrict__ labT,
                                                  int* __restrict__ out) {
  const int t = threadIdx.x, m = blockIdx.x;
  __shared__ unsigned int ent[NENT];
  __shared__ unsigned int smax[256];
  __shared__ unsigned int sbuf[CAPBUF];
  __shared__ unsigned int scnt, sTauA, sE24, ccnt2;
  __shared__ unsigned char flg[NBLKG];
  __shared__ short flist[NBLKG];
  __shared__ int fcnt, sC2;
  __shared__ unsigned int cbuf[128];
  __shared__ int    selC[SELMAX];
  __shared__ double rvs[SELMAX];
  __shared__ double sv2[SELMAX];
  __shared__ int    si2[SELMAX];
  __shared__ double earr[KNN];
  __shared__ double wv[KNN];
  __shared__ int    wi[KNN];

  if (t == 0) { scnt = 0u; fcnt = 0; ccnt2 = 0u; sC2 = 0; }
  for (int i = t; i < NENT; i += 256) ent[i] = toplist[(size_t)m * NENT + i];
  __syncthreads();

  // tauA = 24th largest of per-thread maxima (ties by tid) -> >=24 entries >= tauA
  unsigned int mx = 0u;
  for (int i = t; i < NENT; i += 256) mx = max(mx, ent[i]);
  smax[t] = mx;
  __syncthreads();
  {
    int rnk = 0;
    for (int j = 0; j < 256; ++j)
      rnk += (smax[j] > mx || (smax[j] == mx && j < t)) ? 1 : 0;
    if (rnk == K2 - 1) sTauA = mx;
  }
  __syncthreads();
  const unsigned int tauA = sTauA;

  // collect entries >= tauA; find e24 = 24th-largest entry (u32 unique)
  for (int i = t; i < NENT; i += 256) {
    unsigned int e = ent[i];
    if (e >= tauA) { unsigned int p = atomicAdd(&scnt, 1u); if (p < CAPBUF) sbuf[p] = e; }
  }
  __syncthreads();
  const int C = (int)min(scnt, (unsigned int)CAPBUF);
  for (int s = t; s < C; s += 256) {
    unsigned int e = sbuf[s];
    int rk = 0;
    for (int j = 0; j < C; ++j) rk += (sbuf[j] > e) ? 1 : 0;
    if (rk == K2 - 1) sE24 = e;
  }
  __syncthreads();
  const unsigned int k24 = sE24 >> 16;

  // flag blocks whose 4th shortlist key >= k24 (may hide >4 elems above k24)
  if (t < NBLKG) {
    bool fl = (ent[t * 4 + 3] >> 16) >= k24;
    flg[t] = fl ? 1 : 0;
    if (fl) { int p = atomicAdd(&fcnt, 1); flist[p] = (short)t; }
  }
  __syncthreads();

  // candidates: non-flagged shortlist entries with key >= k24
  for (int i = t; i < NENT; i += 256) {
    unsigned int e = ent[i];
    if ((e >> 16) >= k24) {
      int col = 0xFFFF - (int)(e & 0xFFFFu);
      if (!flg[col >> 8]) { unsigned int p = atomicAdd(&ccnt2, 1u); if (p < 128) cbuf[p] = e; }
    }
  }
  __syncthreads();

  // rescan flagged blocks fully (bf16-rounded f32 dot; 1-ulp slack on key)
  const int FC = fcnt;
  for (int q = 0; q < FC; ++q) {
    const int fb = flist[q];
    const int col = fb * 256 + t;
    if (col < N_TRAIN) {
      const float* Tc = trainT + (size_t)col * DDIM;
      const float* Tr = test + (size_t)m * DDIM;
      float s0 = 0.f;
      for (int k = 0; k < DDIM; ++k)
        s0 = fmaf(bf2f(f2bf(Tr[k])), bf2f(f2bf(Tc[k])), s0);
      unsigned int key = flip32(__float_as_uint(s0)) >> 16;
      if (key + 1u >= k24) {
        unsigned int e = (key << 16) | (0xFFFFu - (unsigned int)col);
        unsigned int p = atomicAdd(&ccnt2, 1u);
        if (p < 128) cbuf[p] = e;
      }
    }
    // col >= N_TRAIN or second half of block handled by other threads; 256 cols == 256 threads
  }
  __syncthreads();
  const int CC = (int)min(ccnt2, 128u);

  // rank-select candidates by (key desc, col asc) == u32 desc -> selC[0..C2)
  for (int s = t; s < CC; s += 256) {
    unsigned int e = cbuf[s];
    int rk = 0;
    for (int j = 0; j < CC; ++j) rk += (cbuf[j] > e) ? 1 : 0;
    if (rk < SELMAX) {
      selC[rk] = 0xFFFF - (int)(e & 0xFFFFu);
      atomicMax(&sC2, rk + 1);
    }
  }
  __syncthreads();
  const int C2 = sC2 < SELMAX ? sC2 : SELMAX;   // >= 20 guaranteed (>=24 cands)

  // ---- f64 refine of C2 cands (4 waves split cands, lanes over d) ----
  const int wid = t >> 6, lane = t & 63;
  float tr[DDIM / 64];
#pragma unroll
  for (int dd = 0; dd < DDIM / 64; ++dd)
    tr[dd] = test[(size_t)m * DDIM + dd * 64 + lane];
#pragma unroll 1
  for (int c = wid; c < C2; c += 4) {
    const float* Tc = trainT + (size_t)selC[c] * DDIM;
    double s = 0.0;
#pragma unroll
    for (int dd = 0; dd < DDIM / 64; ++dd)
      s += (double)tr[dd] * (double)Tc[dd * 64 + lane];
#pragma unroll
    for (int off = 32; off > 0; off >>= 1) s += __shfl_xor(s, off);
    if (lane == 0) rvs[c] = s;
  }
  __syncthreads();

  if (t < C2) {
    double v = rvs[t]; int id = selC[t];
    int r = 0;
    for (int n = 0; n < C2; ++n)
      r += (rvs[n] > v || (rvs[n] == v && selC[n] < id)) ? 1 : 0;
    sv2[r] = v; si2[r] = id;
  }
  __syncthreads();

  if (t < KNN) earr[t] = exp(sv2[t] - sv2[0]);
  __syncthreads();
  if (t < KNN) {
    double ssum = 0.0;
    for (int k = 0; k < KNN; ++k) ssum += earr[k];
    wv[t] = earr[t] / ssum;
    wi[t] = si2[t];
  }
  __syncthreads();

  // ---- per-pixel weighted vote (f64) + argmax ----
  unsigned int packed[5];
#pragma unroll
  for (int q = 0; q < 5; ++q) {
    unsigned int p = 0;
#pragma unroll
    for (int j = 0; j < 4; ++j)
      p |= (unsigned int)labT[(size_t)wi[q * 4 + j] * 256 + t] << (8 * j);
    packed[q] = p;
  }
  double best = -1.0; int bc = 0;
#pragma unroll 1
  for (int c = 0; c < NCLS; ++c) {
    double s = 0.0;
#pragma unroll
    for (int k = 0; k < KNN; ++k) {
      unsigned int lab = (packed[k >> 2] >> ((k & 3) * 8)) & 255u;
      s += (lab == (unsigned int)c) ? wv[k] : 0.0;
    }
    if (s > best) { best = s; bc = c; }
  }
  const int b = m / 196, p = m % 196;
  const int py = p / 14, px = p % 14;
  const int i = t >> 4, j = t & 15;
  out[((size_t)b * 224 + py * 16 + i) * 224 + px * 16 + j] = bc;
}

// ---------------- launch ------------------------------------------------------
// ws layout (bytes), total 134,381,568 (< ~307 MB poisoned ws):
//   labT    @ 0           : 12,800,000
//   Apack   @ 12,800,000  :  1,228,800  (u16 [100][12][64][8])
//   Bpack   @ 14,028,800  : 38,535,168  (u16 [3136][12][64][8])
//   trainT  @ 52,563,968  : 76,800,000  (f32 [50000][384])
//   toplist @ 129,363,968 :  5,017,600  (u32 [1600][196][4])
extern "C" void kernel_launch(void* const* d_in, const int* in_sizes, int n_in,
                              void* d_out, int out_size, void* d_ws, size_t ws_size,
                              hipStream_t stream) {
  const float* test  = (const float*)d_in[0];   // [1568][384]
  const float* train = (const float*)d_in[1];   // [384][50000]
  const int* labels  = (const int*)d_in[2];     // [256][50000]
  int* out = (int*)d_out;
  char* ws = (char*)d_ws;

  unsigned char*  labT    = (unsigned char*)ws;
  unsigned short* Apack   = (unsigned short*)(ws + 12800000);
  unsigned short* Bpack   = (unsigned short*)(ws + 14028800);
  float*          trainT  = (float*)(ws + 52563968);
  unsigned int*   toplist = (unsigned int*)(ws + 129363968);

  transpose_labels<<<dim3(782, 4), 256, 0, stream>>>(labels, labT);
  conv_Apack<<<dim3((MPAD / 16) * 12 * 512 / 256), 256, 0, stream>>>(test, Apack);
  trans_train_fused<<<dim3(784, 6), 256, 0, stream>>>(train, Bpack, trainT);
  mfma_gemm<<<dim3(25 * NBLKG), 256, 0, stream>>>(Apack, Bpack, toplist);
  tail_fused<<<dim3(M_ROWS), 256, 0, stream>>>(toplist, test, trainT, labT, out);
}

// Round 13
// 234.093 us; speedup vs baseline: 1.1151x; 1.0172x over previous
//
#include <hip/hip_runtime.h>
#include <float.h>

#define N_TRAIN 50000
#define NPAD    50176        // padded col count
#define NBLKS   392          // 128-col shortlist blocks
#define MPAD    1664         // 13*128 padded row count
#define DDIM    384
#define M_ROWS  1568         // 8*196
#define KNN     20
#define K2      24           // candidate-inclusion rank (margin over 20)
#define SELMAX  64
#define NCLS    21
#define CAPBUF  768
#define NENT    1568         // 392*4 shortlist entries per row

typedef __attribute__((ext_vector_type(8))) short bf16x8;
typedef __attribute__((ext_vector_type(4))) float f32x4;

#define GLOAD_LDS16(gp, lp) \
  __builtin_amdgcn_global_load_lds((const __attribute__((address_space(1))) void*)(gp), \
                                   (__attribute__((address_space(3))) void*)(lp), 16, 0, 0)

// round-to-nearest-even f32 -> bf16
static __device__ __forceinline__ unsigned short f2bf(float f) {
  unsigned int u = __float_as_uint(f);
  unsigned int r = (u + 0x7fffu + ((u >> 16) & 1u)) >> 16;
  return (unsigned short)r;
}
static __device__ __forceinline__ float bf2f(unsigned short h) {
  return __uint_as_float(((unsigned int)h) << 16);
}
// order-preserving f32 -> u32 key
static __device__ __forceinline__ unsigned int flip32(unsigned int u) {
  return (u & 0x80000000u) ? ~u : (u | 0x80000000u);
}

#define CSW(x, y) { unsigned int _hi = max(x, y); unsigned int _lo = min(x, y); x = _hi; y = _lo; }

// ---------------- transpose labels [256][50000] i32 -> [50000][256] u8 --------
__global__ __launch_bounds__(256) void transpose_labels(const int* __restrict__ labels,
                                                        unsigned char* __restrict__ labT) {
  __shared__ int tile[64][65];
  const int t  = threadIdx.x;
  const int c0 = blockIdx.x * 64;
  const int r0 = blockIdx.y * 64;
#pragma unroll
  for (int i = 0; i < 16; ++i) {
    int idx = i * 256 + t;
    int r = idx >> 6, c = idx & 63;
    int cc = c0 + c;
    tile[r][c] = (cc < N_TRAIN) ? labels[(size_t)(r0 + r) * N_TRAIN + cc] : 0;
  }
  __syncthreads();
#pragma unroll
  for (int i = 0; i < 16; ++i) {
    int idx = i * 256 + t;
    int c = idx >> 6, r = idx & 63;
    int cc = c0 + c;
    if (cc < N_TRAIN) labT[(size_t)cc * 256 + r0 + r] = (unsigned char)tile[r][c];
  }
}

// ------- pack test -> Apack fragment-major: [mt=104][kc=12][lane=64][8] bf16 ---
// element: A[row = mt*16 + (lane&15)][k = kc*32 + (lane>>4)*8 + j]
__global__ __launch_bounds__(256) void conv_Apack(const float* __restrict__ test,
                                                  unsigned short* __restrict__ Apack) {
  int o = blockIdx.x * 256 + threadIdx.x;        // over 104*12*512 = 638,976
  if (o >= (MPAD / 16) * 12 * 512) return;
  int j = o & 7;
  int l = (o >> 3) & 63;
  int kcmt = o >> 9;
  int kc = kcmt % 12, mt = kcmt / 12;
  int row = mt * 16 + (l & 15);
  int k = kc * 32 + (l >> 4) * 8 + j;
  Apack[o] = (row < M_ROWS) ? f2bf(test[(size_t)row * DDIM + k]) : (unsigned short)0;
}

// -- fused: train [384][50000] f32 -> Bpack frag-major bf16 + trainT f32 -------
// Bpack: [nt=3136][kc=12][lane=64][8]; element B[col=nt*16+(l&15)][k=kc*32+(l>>4)*8+j]
__global__ __launch_bounds__(256) void trans_train_fused(const float* __restrict__ train,
                                                         unsigned short* __restrict__ Bpack,
                                                         float* __restrict__ trainT) {
  __shared__ float tile[64][65];   // [k-in-tile][col-in-tile]
  const int t  = threadIdx.x;
  const int c0 = blockIdx.x * 64;   // col base (0..50176)
  const int r0 = blockIdx.y * 64;   // k base (0..384)
#pragma unroll
  for (int i = 0; i < 16; ++i) {
    int idx = i * 256 + t;
    int r = idx >> 6, c = idx & 63;
    int cc = c0 + c;
    tile[r][c] = (cc < N_TRAIN) ? train[(size_t)(r0 + r) * N_TRAIN + cc] : 0.f;
  }
  __syncthreads();
#pragma unroll
  for (int it = 0; it < 2; ++it) {
    int u = it * 256 + t;
    int c = u & 63, koctL = u >> 6;            // koctL 0..7
    int col = c0 + c;
    int koct = (r0 >> 3) + koctL;
    int kc = koct >> 2, l4 = koct & 3;
    int nt = col >> 4, l15 = col & 15;
    size_t base = ((size_t)(nt * 12 + kc) * 64 + l4 * 16 + l15) * 8;
    ushort4 h0, h1;
    h0.x = f2bf(tile[koctL * 8 + 0][c]); h0.y = f2bf(tile[koctL * 8 + 1][c]);
    h0.z = f2bf(tile[koctL * 8 + 2][c]); h0.w = f2bf(tile[koctL * 8 + 3][c]);
    h1.x = f2bf(tile[koctL * 8 + 4][c]); h1.y = f2bf(tile[koctL * 8 + 5][c]);
    h1.z = f2bf(tile[koctL * 8 + 6][c]); h1.w = f2bf(tile[koctL * 8 + 7][c]);
    *(ushort4*)&Bpack[base]     = h0;
    *(ushort4*)&Bpack[base + 4] = h1;
  }
#pragma unroll
  for (int i = 0; i < 16; ++i) {
    int idx = i * 256 + t;
    int c = idx >> 6, r = idx & 63;
    int cc = c0 + c;
    if (cc < N_TRAIN) trainT[(size_t)cc * DDIM + r0 + r] = tile[r][c];
  }
}

// ---------------- MFMA GEMM: A-in-LDS (once per block), B reg-streamed --------
// Block: 128 rows x (2 steps x 512 cols), 8 waves 2x4 (wave 64x128).
// A tile 128x384 bf16 = 96KB LDS, staged once via global_load_lds (linear,
// fragment-major; ds_read is consecutive-per-lane -> conflict-free).
// K-loop has ZERO barriers. Epilogue: wave-private top-4 per 128-col block.
__global__ __launch_bounds__(512, 2) void mfma_gemm(const unsigned short* __restrict__ Apack,
                                                    const unsigned short* __restrict__ Bpack,
                                                    unsigned int* __restrict__ toplist) {
  extern __shared__ unsigned short lds16[];   // A: u16[49152] (96KB); bounce @98304B
  uint4* bounce = (uint4*)((char*)lds16 + 98304);   // [128 rows][4 wc]
  const int t = threadIdx.x;

  // bijective XCD chunking: nwg = 637 = 8*79 + 5
  const int flat = blockIdx.x;
  const int xcd = flat & 7, jj = flat >> 3;
  const int wg = (xcd < 5 ? xcd * 80 : 400 + (xcd - 5) * 79) + jj;
  const int mblk = wg % 13, ngrp = wg / 13;   // 13 consecutive wg share ngrp (B L2-local)
  const int m0 = mblk * 128;

  const int wid = t >> 6, lane = t & 63;
  const int wr = wid >> 2, wc = wid & 3;      // 2 x 4 waves; wave = 64 rows x 128 cols
  const int l15 = lane & 15, l4 = lane >> 4;

  // ---- stage A once: 96KB linear copy of Apack block region ----
  const unsigned short* Asrc = Apack + (size_t)(mblk * 8) * 12 * 512;
#pragma unroll
  for (int j = 0; j < 12; ++j)
    GLOAD_LDS16(Asrc + (size_t)j * 4096 + wid * 512 + lane * 8,
                &lds16[j * 4096 + wid * 512]);
  __syncthreads();   // compiler drains vmcnt before barrier

#pragma unroll 1
  for (int s = 0; s < 2; ++s) {
    const int colbase = ngrp * 1024 + s * 512;
    const unsigned short* Bb = Bpack + (size_t)(colbase / 16 + wc * 8) * 12 * 512;

    f32x4 acc[4][8];
    const f32x4 zero = {0.f, 0.f, 0.f, 0.f};
#pragma unroll
    for (int f = 0; f < 4; ++f)
#pragma unroll
      for (int n = 0; n < 8; ++n) acc[f][n] = zero;

#pragma unroll 2
    for (int kc = 0; kc < 12; ++kc) {
      bf16x8 a[4], b[8];
#pragma unroll
      for (int n = 0; n < 8; ++n)
        b[n] = *(const bf16x8*)&Bb[((size_t)(n * 12 + kc) * 64 + lane) * 8];
#pragma unroll
      for (int f = 0; f < 4; ++f)
        a[f] = *(const bf16x8*)&lds16[((wr * 4 + f) * 12 + kc) * 512 + lane * 8];
#pragma unroll
      for (int f = 0; f < 4; ++f)
#pragma unroll
        for (int n = 0; n < 8; ++n)
          acc[f][n] = __builtin_amdgcn_mfma_f32_16x16x32_bf16(a[f], b[n], acc[f][n], 0, 0, 0);
    }

    // ---- epilogue: wave-private top-4 of its 128 cols, per row ----
#pragma unroll
    for (int f = 0; f < 4; ++f) {
#pragma unroll
      for (int r = 0; r < 4; ++r) {
        unsigned int e[8];
#pragma unroll
        for (int n = 0; n < 8; ++n) {
          int col = colbase + wc * 128 + n * 16 + l15;
          unsigned int k16 = flip32(__float_as_uint(acc[f][n][r])) >> 16;
          e[n] = (col < N_TRAIN) ? ((k16 << 16) | (0xFFFFu - (unsigned int)col)) : 0u;
        }
        // top-4 of 8 in-lane: sort4 + sort4 + bitonic clean + sort4
        CSW(e[0], e[1]); CSW(e[2], e[3]); CSW(e[0], e[2]); CSW(e[1], e[3]); CSW(e[1], e[2]);
        CSW(e[4], e[5]); CSW(e[6], e[7]); CSW(e[4], e[6]); CSW(e[5], e[7]); CSW(e[5], e[6]);
        unsigned int v0 = max(e[0], e[7]), v1 = max(e[1], e[6]);
        unsigned int v2 = max(e[2], e[5]), v3 = max(e[3], e[4]);
        CSW(v0, v2); CSW(v1, v3); CSW(v0, v1); CSW(v2, v3);
        // butterfly merge across the 16 l15-lanes (strides 1,2,4,8)
#pragma unroll
        for (int st = 1; st <= 8; st <<= 1) {
          unsigned int p0 = (unsigned int)__shfl_xor((int)v0, st);
          unsigned int p1 = (unsigned int)__shfl_xor((int)v1, st);
          unsigned int p2 = (unsigned int)__shfl_xor((int)v2, st);
          unsigned int p3 = (unsigned int)__shfl_xor((int)v3, st);
          unsigned int t0 = max(v0, p3), t1 = max(v1, p2);
          unsigned int t2 = max(v2, p1), t3 = max(v3, p0);
          CSW(t0, t2); CSW(t1, t3); CSW(t0, t1); CSW(t2, t3);
          v0 = t0; v1 = t1; v2 = t2; v3 = t3;
        }
        if (l15 == 0) {
          uint4 w; w.x = v0; w.y = v1; w.z = v2; w.w = v3;
          bounce[(wr * 64 + f * 16 + l4 * 4 + r) * 4 + wc] = w;
        }
      }
    }
    __syncthreads();

    // ---- coalesced shortlist writeout: [row][blk*4..+3] ----
    {
      int row = t >> 2, e = t & 3;
      int grow = m0 + row;
      if (grow < M_ROWS) {
        uint4 w = bounce[row * 4 + e];
        int blk = ngrp * 8 + s * 4 + e;
        *(uint4*)&toplist[(size_t)grow * NENT + blk * 4] = w;
      }
    }
    __syncthreads();   // bounce reused next step
  }
}

// --------- fused tail: shortlist select (+rare rescan) -> f64 refine -> vote --
__global__ __launch_bounds__(256) void tail_fused(const unsigned int* __restrict__ toplist,
                                                  const float* __restrict__ test,
                                                  const float* __restrict__ trainT,
                                                  const unsigned char* __restrict__ labT,
                                                  int* __restrict__ out) {
  const int t = threadIdx.x, m = blockIdx.x;
  __shared__ unsigned int ent[NENT];
  __shared__ unsigned int smax[256];
  __shared__ unsigned int sbuf[CAPBUF];
  __shared__ unsigned int scnt, sTauA, sE24, ccnt2;
  __shared__ unsigned char flg[NBLKS];
  __shared__ short flist[64];
  __shared__ int fcnt, sC2;
  __shared__ unsigned int cbuf[128];
  __shared__ int    selC[SELMAX];
  __shared__ double rvs[SELMAX];
  __shared__ double sv2[SELMAX];
  __shared__ int    si2[SELMAX];
  __shared__ double earr[KNN];
  __shared__ double wv[KNN];
  __shared__ int    wi[KNN];

  if (t == 0) { scnt = 0u; fcnt = 0; ccnt2 = 0u; sC2 = 0; }
  for (int i = t; i < NENT; i += 256) ent[i] = toplist[(size_t)m * NENT + i];
  __syncthreads();

  // tauA = 24th largest of per-thread maxima (ties by tid)
  unsigned int mx = 0u;
  for (int i = t; i < NENT; i += 256) mx = max(mx, ent[i]);
  smax[t] = mx;
  __syncthreads();
  {
    int rnk = 0;
    for (int j = 0; j < 256; ++j)
      rnk += (smax[j] > mx || (smax[j] == mx && j < t)) ? 1 : 0;
    if (rnk == K2 - 1) sTauA = mx;
  }
  __syncthreads();
  const unsigned int tauA = sTauA;

  // collect entries >= tauA; find e24 = 24th-largest entry (u32 unique)
  for (int i = t; i < NENT; i += 256) {
    unsigned int e = ent[i];
    if (e >= tauA) { unsigned int p = atomicAdd(&scnt, 1u); if (p < CAPBUF) sbuf[p] = e; }
  }
  __syncthreads();
  const int C = (int)min(scnt, (unsigned int)CAPBUF);
  for (int s = t; s < C; s += 256) {
    unsigned int e = sbuf[s];
    int rk = 0;
    for (int j = 0; j < C; ++j) rk += (sbuf[j] > e) ? 1 : 0;
    if (rk == K2 - 1) sE24 = e;
  }
  __syncthreads();
  const unsigned int k24 = sE24 >> 16;

  // flag blocks whose 4th shortlist key >= k24 (may hide >4 elems above k24)
  for (int i = t; i < NBLKS; i += 256) {
    bool fl = (ent[i * 4 + 3] >> 16) >= k24;
    flg[i] = fl ? 1 : 0;
    if (fl) { int p = atomicAdd(&fcnt, 1); if (p < 64) flist[p] = (short)i; }
  }
  __syncthreads();

  // candidates: non-flagged shortlist entries with key >= k24
  for (int i = t; i < NENT; i += 256) {
    unsigned int e = ent[i];
    if ((e >> 16) >= k24) {
      int col = 0xFFFF - (int)(e & 0xFFFFu);
      if (!flg[col >> 7]) { unsigned int p = atomicAdd(&ccnt2, 1u); if (p < 128) cbuf[p] = e; }
    }
  }
  __syncthreads();

  // rescan flagged blocks fully (bf16-rounded f32 dot; 1-ulp slack on key)
  const int FC = min(fcnt, 64);
  for (int q = 0; q < FC; ++q) {
    const int fb = flist[q];
    const int col = fb * 128 + t;
    if (t < 128 && col < N_TRAIN) {
      const float* Tc = trainT + (size_t)col * DDIM;
      const float* Tr = test + (size_t)m * DDIM;
      float s0 = 0.f;
      for (int k = 0; k < DDIM; ++k)
        s0 = fmaf(bf2f(f2bf(Tr[k])), bf2f(f2bf(Tc[k])), s0);
      unsigned int key = flip32(__float_as_uint(s0)) >> 16;
      if (key + 1u >= k24) {
        unsigned int e = (key << 16) | (0xFFFFu - (unsigned int)col);
        unsigned int p = atomicAdd(&ccnt2, 1u);
        if (p < 128) cbuf[p] = e;
      }
    }
  }
  __syncthreads();
  const int CC = (int)min(ccnt2, 128u);

  // rank-select candidates by (key desc, col asc) == u32 desc -> selC[0..C2)
  for (int s = t; s < CC; s += 256) {
    unsigned int e = cbuf[s];
    int rk = 0;
    for (int j = 0; j < CC; ++j) rk += (cbuf[j] > e) ? 1 : 0;
    if (rk < SELMAX) {
      selC[rk] = 0xFFFF - (int)(e & 0xFFFFu);
      atomicMax(&sC2, rk + 1);
    }
  }
  __syncthreads();
  const int C2 = sC2 < SELMAX ? sC2 : SELMAX;   // >= 20 guaranteed (>=24 cands)

  // ---- f64 refine of C2 cands (4 waves split cands, lanes over d) ----
  const int wid = t >> 6, lane = t & 63;
  float tr[DDIM / 64];
#pragma unroll
  for (int dd = 0; dd < DDIM / 64; ++dd)
    tr[dd] = test[(size_t)m * DDIM + dd * 64 + lane];
#pragma unroll 1
  for (int c = wid; c < C2; c += 4) {
    const float* Tc = trainT + (size_t)selC[c] * DDIM;
    double s = 0.0;
#pragma unroll
    for (int dd = 0; dd < DDIM / 64; ++dd)
      s += (double)tr[dd] * (double)Tc[dd * 64 + lane];
#pragma unroll
    for (int off = 32; off > 0; off >>= 1) s += __shfl_xor(s, off);
    if (lane == 0) rvs[c] = s;
  }
  __syncthreads();

  if (t < C2) {
    double v = rvs[t]; int id = selC[t];
    int r = 0;
    for (int n = 0; n < C2; ++n)
      r += (rvs[n] > v || (rvs[n] == v && selC[n] < id)) ? 1 : 0;
    sv2[r] = v; si2[r] = id;
  }
  __syncthreads();

  if (t < KNN) earr[t] = exp(sv2[t] - sv2[0]);
  __syncthreads();
  if (t < KNN) {
    double ssum = 0.0;
    for (int k = 0; k < KNN; ++k) ssum += earr[k];
    wv[t] = earr[t] / ssum;
    wi[t] = si2[t];
  }
  __syncthreads();

  // ---- per-pixel weighted vote (f64) + argmax ----
  unsigned int packed[5];
#pragma unroll
  for (int q = 0; q < 5; ++q) {
    unsigned int p = 0;
#pragma unroll
    for (int j = 0; j < 4; ++j)
      p |= (unsigned int)labT[(size_t)wi[q * 4 + j] * 256 + t] << (8 * j);
    packed[q] = p;
  }
  double best = -1.0; int bc = 0;
#pragma unroll 1
  for (int c = 0; c < NCLS; ++c) {
    double s = 0.0;
#pragma unroll
    for (int k = 0; k < KNN; ++k) {
      unsigned int lab = (packed[k >> 2] >> ((k & 3) * 8)) & 255u;
      s += (lab == (unsigned int)c) ? wv[k] : 0.0;
    }
    if (s > best) { best = s; bc = c; }
  }
  const int b = m / 196, p = m % 196;
  const int py = p / 14, px = p % 14;
  const int i = t >> 4, j = t & 15;
  out[((size_t)b * 224 + py * 16 + i) * 224 + px * 16 + j] = bc;
}

// ---------------- launch ------------------------------------------------------
// ws layout (bytes), total 139,247,616 (< ~307 MB poisoned ws):
//   labT    @ 0           : 12,800,000
//   Apack   @ 12,800,000  :  1,277,952  (u16 [104][12][64][8])
//   Bpack   @ 14,077,952  : 38,535,168  (u16 [3136][12][64][8])
//   trainT  @ 52,613,120  : 76,800,000  (f32 [50000][384])
//   toplist @ 129,413,120 :  9,834,496  (u32 [1568][1568])
extern "C" void kernel_launch(void* const* d_in, const int* in_sizes, int n_in,
                              void* d_out, int out_size, void* d_ws, size_t ws_size,
                              hipStream_t stream) {
  const float* test  = (const float*)d_in[0];   // [1568][384]
  const float* train = (const float*)d_in[1];   // [384][50000]
  const int* labels  = (const int*)d_in[2];     // [256][50000]
  int* out = (int*)d_out;
  char* ws = (char*)d_ws;

  unsigned char*  labT    = (unsigned char*)ws;
  unsigned short* Apack   = (unsigned short*)(ws + 12800000);
  unsigned short* Bpack   = (unsigned short*)(ws + 14077952);
  float*          trainT  = (float*)(ws + 52613120);
  unsigned int*   toplist = (unsigned int*)(ws + 129413120);

  transpose_labels<<<dim3(782, 4), 256, 0, stream>>>(labels, labT);
  conv_Apack<<<dim3((MPAD / 16) * 12 * 512 / 256), 256, 0, stream>>>(test, Apack);
  trans_train_fused<<<dim3(784, 6), 256, 0, stream>>>(train, Bpack, trainT);
  mfma_gemm<<<dim3(637), 512, 106496, stream>>>(Apack, Bpack, toplist);
  tail_fused<<<dim3(M_ROWS), 256, 0, stream>>>(toplist, test, trainT, labT, out);
}